// Round 2
// baseline (1436.045 us; speedup 1.0000x reference)
//
#include <hip/hip_runtime.h>
#include <hip/hip_bf16.h>
#include <stdint.h>

// ParaGraph: 2 node types (net/cell, N=100000), 3 relations (E=600000 each), D=128.
// I/O is FP32 (reference dtype). Internally: bf16 MFMA for GEMMs, fp32 accumulation.
#define NN 100000
#define NE 600000
#define SP 136   // LDS row stride in ushorts: 128 + 8 pad

typedef unsigned short u16;
typedef __attribute__((ext_vector_type(8))) short short8;
typedef __attribute__((ext_vector_type(8))) __bf16 bf16x8;
typedef __attribute__((ext_vector_type(4))) float floatx4;

__device__ __forceinline__ float b2f(u16 u) {
  union { float f; unsigned int i; } c; c.i = ((unsigned int)u) << 16; return c.f;
}
__device__ __forceinline__ u16 f2b(float f) {
  union { float f; unsigned int i; } c; c.f = f;
  unsigned int r = c.i + 0x7FFFu + ((c.i >> 16) & 1u);  // RNE
  return (u16)(r >> 16);
}

// ---------- feature projection: feat = x @ Wp.T, [N,16]x[16,128] -> bf16 [N,128]
__global__ __launch_bounds__(256) void proj_k(const float* __restrict__ x_net, const float* __restrict__ x_cell,
                                              const float* __restrict__ Wp_net, const float* __restrict__ Wp_cell,
                                              u16* __restrict__ feat_net, u16* __restrict__ feat_cell) {
  const float* x  = blockIdx.y ? x_cell : x_net;
  const float* Wp = blockIdx.y ? Wp_cell : Wp_net;
  u16* feat       = blockIdx.y ? feat_cell : feat_net;
  __shared__ float Ws[128 * 17];
  __shared__ float xs[16][17];
  int tid = threadIdx.x;
#pragma unroll
  for (int it = 0; it < 8; ++it) {
    int idx = it * 256 + tid;           // = j*16 + k over 128x16
    int j = idx >> 4, k = idx & 15;
    Ws[j * 17 + k] = Wp[idx];
  }
  int n0 = blockIdx.x * 16;             // NN divisible by 16
  { int nn = tid >> 4, k = tid & 15;
    xs[nn][k] = x[(size_t)(n0 + nn) * 16 + k]; }
  __syncthreads();
  int j = tid & 127, g = tid >> 7;
  float acc[8];
#pragma unroll
  for (int r = 0; r < 8; ++r) acc[r] = 0.f;
#pragma unroll
  for (int k = 0; k < 16; ++k) {
    float w = Ws[j * 17 + k];
#pragma unroll
    for (int r = 0; r < 8; ++r) acc[r] += xs[g * 8 + r][k] * w;
  }
#pragma unroll
  for (int r = 0; r < 8; ++r)
    feat[(size_t)(n0 + g * 8 + r) * 128 + j] = f2b(acc[r]);
}

// ---------- attention logit vectors: vecs[a] = Wg_r.T @ (al or ar), 6 x [128]
__global__ __launch_bounds__(128) void vec_k(const float* Wg0, const float* al0, const float* ar0,
                                             const float* Wg1, const float* al1, const float* ar1,
                                             const float* Wg2, const float* al2, const float* ar2,
                                             float* __restrict__ vecs) {
  int a = blockIdx.x;  // 0..5 : wal0,war0,wal1,war1,wal2,war2
  const float* W = (a < 2) ? Wg0 : (a < 4) ? Wg1 : Wg2;
  const float* v = (a == 0) ? al0 : (a == 1) ? ar0 : (a == 2) ? al1 : (a == 3) ? ar1 : (a == 4) ? al2 : ar2;
  int j = threadIdx.x;
  float s = 0.f;
  for (int i = 0; i < 128; ++i) s += W[i * 128 + j] * v[i];
  vecs[a * 128 + j] = s;
}

// ---------- per-node logits: outs[a][n] = dot(feat_type(a)[n], vecs[a])
__global__ __launch_bounds__(256) void logits_k(const u16* __restrict__ feat_net, const u16* __restrict__ feat_cell,
                                                const float* __restrict__ vecs, float* __restrict__ outs) {
  int a = blockIdx.y;
  // a: 0 el0(cell) 1 er0(net) 2 el1(net) 3 er1(cell) 4 el2(net) 5 er2(net)
  const u16* f = (a == 0 || a == 3) ? feat_cell : feat_net;
  __shared__ float vs[128];
  if (threadIdx.x < 128) vs[threadIdx.x] = vecs[a * 128 + threadIdx.x];
  __syncthreads();
  int n = blockIdx.x * 256 + threadIdx.x;
  if (n >= NN) return;
  const u16* row = f + (size_t)n * 128;
  float s = 0.f;
#pragma unroll
  for (int k = 0; k < 128; k += 8) {
    short8 u = *(const short8*)(row + k);
#pragma unroll
    for (int t = 0; t < 8; ++t) s += b2f((u16)u[t]) * vs[k + t];
  }
  outs[(size_t)a * NN + n] = s;
}

// ---------- per-edge unnormalized softmax weight + denominator
__global__ __launch_bounds__(256) void edge_ex_k(const float* __restrict__ eln, const float* __restrict__ ern,
                                                 const int* __restrict__ src, const int* __restrict__ dst,
                                                 float* __restrict__ ex, float* __restrict__ denom) {
  int e = blockIdx.x * 256 + threadIdx.x;
  if (e >= NE) return;
  float s = eln[src[e]] + ern[dst[e]];
  float l = (s >= 0.f) ? s : 0.2f * s;          // leaky_relu slope 0.2
  float x = __expf(l);                          // max-subtraction cancels in alpha; |l|<~8 so safe
  ex[e] = x;
  atomicAdd(&denom[dst[e]], x);
}

// ---------- message aggregation: out[dst] += (ex/denom[dst]) * h[src]   (fp32 atomics)
__global__ __launch_bounds__(256) void agg_k(const u16* __restrict__ h, const float* __restrict__ ex,
                                             const float* __restrict__ denom,
                                             const int* __restrict__ src, const int* __restrict__ dst,
                                             float* __restrict__ out) {
  int e = blockIdx.x * 2 + (threadIdx.x >> 7);  // NE even, grid = NE/2
  int d = threadIdx.x & 127;
  int sN = src[e], tN = dst[e];
  float alpha = ex[e] / denom[tN];
  float v = alpha * b2f(h[(size_t)sN * 128 + d]);
  atomicAdd(&out[(size_t)tN * 128 + d], v);
}

// ---------- MFMA GEMM: C[n][j] = act( P?[n][j] + sum_k (A[n][k]+bias?[k]) * W[j*ldw+woff+k] )
// A: bf16 workspace (A_F32=0) or fp32 (A_F32=1). W: fp32 input weights, converted to bf16 in LDS.
// 64 nodes x 128 cols per block, K=128 fully in LDS. In-place (Cv==Av) is safe per-block.
template<int A_F32, int BIAS, int ADDP, int RELU, int OUT_BF16>
__global__ __launch_bounds__(256) void gemm_k(const void* __restrict__ Av,
                                              const float* __restrict__ W, int ldw, int woff,
                                              const float* __restrict__ bias, const u16* __restrict__ P,
                                              void* __restrict__ Cv) {
  __shared__ u16 Alds[64 * SP];
  __shared__ u16 Wlds[128 * SP];
  const int tid = threadIdx.x;
  const int row0 = blockIdx.x * 64;
  // stage W (128x128 fp32 -> bf16), coalesced float4
#pragma unroll
  for (int it = 0; it < 16; ++it) {
    int idx = it * 256 + tid;           // 0..4095
    int r = idx >> 5, c = (idx & 31) << 2;
    float4 v = *(const float4*)(W + (size_t)r * ldw + woff + c);
    ushort4 p; p.x = f2b(v.x); p.y = f2b(v.y); p.z = f2b(v.z); p.w = f2b(v.w);
    *(ushort4*)(&Wlds[r * SP + c]) = p;
  }
  if (A_F32) {
    const float* A = (const float*)Av;
#pragma unroll
    for (int it = 0; it < 8; ++it) {
      int idx = it * 256 + tid;         // 0..2047
      int r = idx >> 5, col = (idx & 31) << 2;
      int gr = row0 + r;
      float4 v = make_float4(0.f, 0.f, 0.f, 0.f);
      if (gr < NN) v = *(const float4*)(A + (size_t)gr * 128 + col);
      if (BIAS) { v.x += bias[col]; v.y += bias[col + 1]; v.z += bias[col + 2]; v.w += bias[col + 3]; }
      ushort4 p; p.x = f2b(v.x); p.y = f2b(v.y); p.z = f2b(v.z); p.w = f2b(v.w);
      *(ushort4*)(&Alds[r * SP + col]) = p;
    }
  } else {
    const u16* A = (const u16*)Av;
#pragma unroll
    for (int it = 0; it < 4; ++it) {
      int idx = it * 256 + tid;         // 0..1023
      int r = idx >> 4, c = (idx & 15) << 3;
      int gr = row0 + r;
      short8 v = short8{0, 0, 0, 0, 0, 0, 0, 0};
      if (gr < NN) v = *(const short8*)(A + (size_t)gr * 128 + c);
      *(short8*)(&Alds[r * SP + c]) = v;
    }
  }
  __syncthreads();
  const int lane = tid & 63, wv = tid >> 6;
  const int m16 = lane & 15, quad = lane >> 4;
  floatx4 acc[8];
#pragma unroll
  for (int c = 0; c < 8; ++c) acc[c] = floatx4{0.f, 0.f, 0.f, 0.f};
  const u16* arow = &Alds[(wv * 16 + m16) * SP + quad * 8];
  const u16* brow = &Wlds[m16 * SP + quad * 8];
#pragma unroll
  for (int kk = 0; kk < 4; ++kk) {
    bf16x8 a = *(const bf16x8*)(arow + kk * 32);
#pragma unroll
    for (int c = 0; c < 8; ++c) {
      bf16x8 b = *(const bf16x8*)(brow + c * 16 * SP + kk * 32);
      acc[c] = __builtin_amdgcn_mfma_f32_16x16x32_bf16(a, b, acc[c], 0, 0, 0);
    }
  }
  // C/D layout (m89-verified): col = lane&15, row = quad*4 + reg
#pragma unroll
  for (int c = 0; c < 8; ++c) {
    int col = c * 16 + m16;
#pragma unroll
    for (int r = 0; r < 4; ++r) {
      int grow = row0 + wv * 16 + quad * 4 + r;
      if (grow < NN) {
        float v = acc[c][r];
        if (ADDP) v += b2f(P[(size_t)grow * 128 + col]);
        if (RELU) v = fmaxf(v, 0.f);
        if (OUT_BF16) ((u16*)Cv)[(size_t)grow * 128 + col] = f2b(v);
        else          ((float*)Cv)[(size_t)grow * 128 + col] = v;
      }
    }
  }
}

extern "C" void kernel_launch(void* const* d_in, const int* in_sizes, int n_in,
                              void* d_out, int out_size, void* d_ws, size_t ws_size,
                              hipStream_t stream) {
  const float* x_net   = (const float*)d_in[0];
  const float* x_cell  = (const float*)d_in[1];
  const float* Wp_net  = (const float*)d_in[2];
  const float* Wp_cell = (const float*)d_in[3];
  const float* Wg[3] = {(const float*)d_in[4], (const float*)d_in[7], (const float*)d_in[10]};
  const float* al[3] = {(const float*)d_in[5], (const float*)d_in[8], (const float*)d_in[11]};
  const float* ar[3] = {(const float*)d_in[6], (const float*)d_in[9], (const float*)d_in[12]};
  const float* Wl    = (const float*)d_in[13];
  const float* bias  = (const float*)d_in[14];
  const int* src[3] = {(const int*)d_in[15], (const int*)d_in[17], (const int*)d_in[19]};
  const int* dst[3] = {(const int*)d_in[16], (const int*)d_in[18], (const int*)d_in[20]};

  char* ws = (char*)d_ws;
  size_t off = 0;
  auto alloc = [&](size_t b) { void* p = ws + off; off = (off + b + 255) & ~(size_t)255; return p; };
  u16*  feat_net  = (u16*)alloc((size_t)NN * 128 * 2);
  u16*  feat_cell = (u16*)alloc((size_t)NN * 128 * 2);
  u16*  hbuf      = (u16*)alloc((size_t)NN * 128 * 2);   // reused per relation
  u16*  P_net     = (u16*)alloc((size_t)NN * 128 * 2);
  u16*  P_cell    = (u16*)alloc((size_t)NN * 128 * 2);
  float* buf_net  = (float*)alloc((size_t)NN * 128 * 4); // running out['net'] (fp32: atomic target)
  float* buf_cell = (float*)alloc((size_t)NN * 128 * 4);
  float* vecs     = (float*)alloc(6 * 128 * 4);
  float* logit    = (float*)alloc((size_t)6 * NN * 4);   // el_r at 2r, er_r at 2r+1
  float* exbuf    = (float*)alloc((size_t)NE * 4);
  float* denom    = (float*)alloc((size_t)3 * NN * 4);

  hipMemsetAsync(buf_net, 0, (size_t)NN * 128 * 4, stream);
  hipMemsetAsync(buf_cell, 0, (size_t)NN * 128 * 4, stream);
  hipMemsetAsync(denom, 0, (size_t)3 * NN * 4, stream);

  proj_k<<<dim3(NN / 16, 2), 256, 0, stream>>>(x_net, x_cell, Wp_net, Wp_cell, feat_net, feat_cell);
  vec_k<<<6, 128, 0, stream>>>(Wg[0], al[0], ar[0], Wg[1], al[1], ar[1], Wg[2], al[2], ar[2], vecs);
  logits_k<<<dim3((NN + 255) / 256, 6), 256, 0, stream>>>(feat_net, feat_cell, vecs, logit);

  const int gb = (NN + 63) / 64;  // 1563
  // P_nt = feat_nt @ W1.T  (W1 = Wl[:, :128])
  gemm_k<0, 0, 0, 0, 1><<<gb, 256, 0, stream>>>(feat_net, Wl, 256, 0, nullptr, nullptr, P_net);
  gemm_k<0, 0, 0, 0, 1><<<gb, 256, 0, stream>>>(feat_cell, Wl, 256, 0, nullptr, nullptr, P_cell);

  const u16* srcfeat[3] = {feat_cell, feat_net, feat_net};
  float* aggout[3] = {buf_net, buf_cell, buf_net};
  for (int r = 0; r < 3; ++r) {
    // h = feat_src @ Wg_r.T (bf16, consumed by gather)
    gemm_k<0, 0, 0, 0, 1><<<gb, 256, 0, stream>>>(srcfeat[r], Wg[r], 128, 0, nullptr, nullptr, hbuf);
    edge_ex_k<<<(NE + 255) / 256, 256, 0, stream>>>(logit + (size_t)(2 * r) * NN, logit + (size_t)(2 * r + 1) * NN,
                                                    src[r], dst[r], exbuf, denom + (size_t)r * NN);
    agg_k<<<NE / 2, 256, 0, stream>>>(hbuf, exbuf, denom + (size_t)r * NN, src[r], dst[r], aggout[r]);
    // fused concat-linear-relu for BOTH ntypes (in-place; W2 = Wl[:, 128:])
    if (r < 2) {
      gemm_k<1, 1, 1, 1, 0><<<gb, 256, 0, stream>>>(buf_net, Wl, 256, 128, bias, P_net, buf_net);
      gemm_k<1, 1, 1, 1, 0><<<gb, 256, 0, stream>>>(buf_cell, Wl, 256, 128, bias, P_cell, buf_cell);
    } else {
      float* out_f = (float*)d_out;  // [2,N,D] fp32: net then cell
      gemm_k<1, 1, 1, 1, 0><<<gb, 256, 0, stream>>>(buf_net, Wl, 256, 128, bias, P_net, out_f);
      gemm_k<1, 1, 1, 1, 0><<<gb, 256, 0, stream>>>(buf_cell, Wl, 256, 128, bias, P_cell, out_f + (size_t)NN * 128);
    }
  }
}

// Round 3
// 1214.404 us; speedup vs baseline: 1.1825x; 1.1825x over previous
//
#include <hip/hip_runtime.h>
#include <hip/hip_bf16.h>
#include <stdint.h>

// ParaGraph: 2 node types (net/cell, N=100000), 3 relations (E=600000 each), D=128.
// I/O FP32. Internals: bf16 MFMA GEMMs; CSR-gather softmax-aggregation (no fp32 atomics).
#define NN 100000
#define NE 600000
#define SP 136   // LDS row stride in ushorts: 128 + 8 pad

typedef unsigned short u16;
typedef unsigned int u32;
typedef __attribute__((ext_vector_type(8))) short short8;
typedef __attribute__((ext_vector_type(8))) __bf16 bf16x8;
typedef __attribute__((ext_vector_type(4))) float floatx4;

__device__ __forceinline__ float b2f(u16 u) {
  union { float f; u32 i; } c; c.i = ((u32)u) << 16; return c.f;
}
__device__ __forceinline__ u16 f2b(float f) {
  union { float f; u32 i; } c; c.f = f;
  u32 r = c.i + 0x7FFFu + ((c.i >> 16) & 1u);  // RNE
  return (u16)(r >> 16);
}

// ---------- feature projection: feat = x @ Wp.T, [N,16]x[16,128] -> bf16 [N,128]
__global__ __launch_bounds__(256) void proj_k(const float* __restrict__ x_net, const float* __restrict__ x_cell,
                                              const float* __restrict__ Wp_net, const float* __restrict__ Wp_cell,
                                              u16* __restrict__ feat_net, u16* __restrict__ feat_cell) {
  const float* x  = blockIdx.y ? x_cell : x_net;
  const float* Wp = blockIdx.y ? Wp_cell : Wp_net;
  u16* feat       = blockIdx.y ? feat_cell : feat_net;
  __shared__ float Ws[128 * 17];
  __shared__ float xs[16][17];
  int tid = threadIdx.x;
#pragma unroll
  for (int it = 0; it < 8; ++it) {
    int idx = it * 256 + tid;           // j*16 + k over 128x16
    int j = idx >> 4, k = idx & 15;
    Ws[j * 17 + k] = Wp[idx];
  }
  int n0 = blockIdx.x * 16;
  { int nn = tid >> 4, k = tid & 15;
    xs[nn][k] = x[(size_t)(n0 + nn) * 16 + k]; }
  __syncthreads();
  int j = tid & 127, g = tid >> 7;
  float acc[8];
#pragma unroll
  for (int r = 0; r < 8; ++r) acc[r] = 0.f;
#pragma unroll
  for (int k = 0; k < 16; ++k) {
    float w = Ws[j * 17 + k];
#pragma unroll
    for (int r = 0; r < 8; ++r) acc[r] += xs[g * 8 + r][k] * w;
  }
#pragma unroll
  for (int r = 0; r < 8; ++r)
    feat[(size_t)(n0 + g * 8 + r) * 128 + j] = f2b(acc[r]);
}

// ---------- attention logit vectors: vecs[a] = Wg_r.T @ (al or ar), 6 x [128]
__global__ __launch_bounds__(128) void vec_k(const float* Wg0, const float* al0, const float* ar0,
                                             const float* Wg1, const float* al1, const float* ar1,
                                             const float* Wg2, const float* al2, const float* ar2,
                                             float* __restrict__ vecs) {
  int a = blockIdx.x;
  const float* W = (a < 2) ? Wg0 : (a < 4) ? Wg1 : Wg2;
  const float* v = (a == 0) ? al0 : (a == 1) ? ar0 : (a == 2) ? al1 : (a == 3) ? ar1 : (a == 4) ? al2 : ar2;
  int j = threadIdx.x;
  float s = 0.f;
  for (int i = 0; i < 128; ++i) s += W[i * 128 + j] * v[i];
  vecs[a * 128 + j] = s;
}

// ---------- per-node logits: outs[a][n] = dot(feat_type(a)[n], vecs[a])
__global__ __launch_bounds__(256) void logits_k(const u16* __restrict__ feat_net, const u16* __restrict__ feat_cell,
                                                const float* __restrict__ vecs, float* __restrict__ outs) {
  int a = blockIdx.y;
  // a: 0 el0(cell) 1 er0(net) 2 el1(net) 3 er1(cell) 4 el2(net) 5 er2(net)
  const u16* f = (a == 0 || a == 3) ? feat_cell : feat_net;
  __shared__ float vs[128];
  if (threadIdx.x < 128) vs[threadIdx.x] = vecs[a * 128 + threadIdx.x];
  __syncthreads();
  int n = blockIdx.x * 256 + threadIdx.x;
  if (n >= NN) return;
  const u16* row = f + (size_t)n * 128;
  float s = 0.f;
#pragma unroll
  for (int k = 0; k < 128; k += 8) {
    short8 u = *(const short8*)(row + k);
#pragma unroll
    for (int t = 0; t < 8; ++t) s += b2f((u16)u[t]) * vs[k + t];
  }
  outs[(size_t)a * NN + n] = s;
}

// ---------- CSR build: histogram of dst
__global__ __launch_bounds__(256) void hist_k(const int* __restrict__ dst0, const int* __restrict__ dst1,
                                              const int* __restrict__ dst2, int* __restrict__ deg) {
  int r = blockIdx.y;
  const int* dst = (r == 0) ? dst0 : (r == 1) ? dst1 : dst2;
  int e = blockIdx.x * 256 + threadIdx.x;
  if (e >= NE) return;
  atomicAdd(&deg[r * NN + dst[e]], 1);
}

// ---------- CSR build: exclusive scan (one block of 1024 per relation)
__global__ __launch_bounds__(1024) void scan_k(const int* __restrict__ deg, int* __restrict__ rowptr,
                                               int* __restrict__ cursor) {
  int r = blockIdx.x;
  const int* d = deg + (size_t)r * NN;
  int* rp = rowptr + (size_t)r * (NN + 1);
  int* cur = cursor + (size_t)r * NN;
  __shared__ int sums[1024];
  int t = threadIdx.x;
  const int CH = 98;                    // 1024*98 = 100352 >= NN
  int base = t * CH;
  int s = 0;
  for (int i = 0; i < CH; ++i) { int idx = base + i; if (idx < NN) s += d[idx]; }
  sums[t] = s; __syncthreads();
  for (int off = 1; off < 1024; off <<= 1) {   // inclusive Hillis-Steele
    int v = (t >= off) ? sums[t - off] : 0;
    __syncthreads();
    sums[t] += v;
    __syncthreads();
  }
  int run = (t == 0) ? 0 : sums[t - 1];
  for (int i = 0; i < CH; ++i) {
    int idx = base + i;
    if (idx < NN) { int dv = d[idx]; rp[idx] = run; cur[idx] = run; run += dv; }
  }
  if (t == 1023) rp[NN] = sums[1023];
}

// ---------- CSR build: scatter {src, ex=exp(leaky(el+er))} into dst-sorted slots
__global__ __launch_bounds__(256) void scatter_k(const int* __restrict__ src0, const int* __restrict__ dst0,
                                                 const int* __restrict__ src1, const int* __restrict__ dst1,
                                                 const int* __restrict__ src2, const int* __restrict__ dst2,
                                                 const float* __restrict__ logit,
                                                 int* __restrict__ cursor, int2* __restrict__ pairs) {
  int r = blockIdx.y;
  const int* src = (r == 0) ? src0 : (r == 1) ? src1 : src2;
  const int* dst = (r == 0) ? dst0 : (r == 1) ? dst1 : dst2;
  int e = blockIdx.x * 256 + threadIdx.x;
  if (e >= NE) return;
  int sN = src[e], dN = dst[e];
  float t = logit[(size_t)(2 * r) * NN + sN] + logit[(size_t)(2 * r + 1) * NN + dN];
  float l = (t >= 0.f) ? t : 0.2f * t;          // leaky_relu 0.2
  float x = __expf(l);                          // max-subtract cancels in alpha; |l| small
  int pos = atomicAdd(&cursor[(size_t)r * NN + dN], 1);
  union { float f; int i; } c; c.f = x;
  pairs[(size_t)r * NE + pos] = make_int2(sN, c.i);
}

// ---------- aggregation: one wave per dst node; out[n] += (sum ex*h[src]) / (sum ex)
__global__ __launch_bounds__(256) void agg_csr_k(const u16* __restrict__ h, const int2* __restrict__ pairs,
                                                 const int* __restrict__ rp, float* __restrict__ out) {
  int n = blockIdx.x * 4 + (threadIdx.x >> 6);
  if (n >= NN) return;
  int lane = threadIdx.x & 63;
  int start = rp[n], end = rp[n + 1];
  if (start == end) return;
  float2 acc = make_float2(0.f, 0.f);
  float s = 0.f;
  for (int e = start; e < end; ++e) {
    int2 p = pairs[e];                          // broadcast (same addr all lanes)
    union { int i; float f; } c; c.i = p.y;
    float x = c.f;
    s += x;
    u32 hv = *(const u32*)(h + (size_t)p.x * 128 + 2 * lane);  // 256B coalesced gather
    acc.x += x * b2f((u16)(hv & 0xffff));
    acc.y += x * b2f((u16)(hv >> 16));
  }
  float inv = 1.f / s;
  float2* o = (float2*)(out + (size_t)n * 128 + 2 * lane);
  float2 prev = *o;
  prev.x += acc.x * inv; prev.y += acc.y * inv;
  *o = prev;
}

// ---------- MFMA GEMM: C[n][j] = act( P?[n][j] + sum_k (A[n][k]+bias?[k]) * W[j*ldw+woff+k] )
template<int A_F32, int BIAS, int ADDP, int RELU, int OUT_BF16>
__global__ __launch_bounds__(256) void gemm_k(const void* __restrict__ Av,
                                              const float* __restrict__ W, int ldw, int woff,
                                              const float* __restrict__ bias, const u16* __restrict__ P,
                                              void* __restrict__ Cv) {
  __shared__ u16 Alds[64 * SP];
  __shared__ u16 Wlds[128 * SP];
  const int tid = threadIdx.x;
  const int row0 = blockIdx.x * 64;
#pragma unroll
  for (int it = 0; it < 16; ++it) {
    int idx = it * 256 + tid;
    int r = idx >> 5, c = (idx & 31) << 2;
    float4 v = *(const float4*)(W + (size_t)r * ldw + woff + c);
    ushort4 p; p.x = f2b(v.x); p.y = f2b(v.y); p.z = f2b(v.z); p.w = f2b(v.w);
    *(ushort4*)(&Wlds[r * SP + c]) = p;
  }
  if (A_F32) {
    const float* A = (const float*)Av;
#pragma unroll
    for (int it = 0; it < 8; ++it) {
      int idx = it * 256 + tid;
      int r = idx >> 5, col = (idx & 31) << 2;
      int gr = row0 + r;
      float4 v = make_float4(0.f, 0.f, 0.f, 0.f);
      if (gr < NN) v = *(const float4*)(A + (size_t)gr * 128 + col);
      if (BIAS) { v.x += bias[col]; v.y += bias[col + 1]; v.z += bias[col + 2]; v.w += bias[col + 3]; }
      ushort4 p; p.x = f2b(v.x); p.y = f2b(v.y); p.z = f2b(v.z); p.w = f2b(v.w);
      *(ushort4*)(&Alds[r * SP + col]) = p;
    }
  } else {
    const u16* A = (const u16*)Av;
#pragma unroll
    for (int it = 0; it < 4; ++it) {
      int idx = it * 256 + tid;
      int r = idx >> 4, c = (idx & 15) << 3;
      int gr = row0 + r;
      short8 v = short8{0, 0, 0, 0, 0, 0, 0, 0};
      if (gr < NN) v = *(const short8*)(A + (size_t)gr * 128 + c);
      *(short8*)(&Alds[r * SP + c]) = v;
    }
  }
  __syncthreads();
  const int lane = tid & 63, wv = tid >> 6;
  const int m16 = lane & 15, quad = lane >> 4;
  floatx4 acc[8];
#pragma unroll
  for (int c = 0; c < 8; ++c) acc[c] = floatx4{0.f, 0.f, 0.f, 0.f};
  const u16* arow = &Alds[(wv * 16 + m16) * SP + quad * 8];
  const u16* brow = &Wlds[m16 * SP + quad * 8];
#pragma unroll
  for (int kk = 0; kk < 4; ++kk) {
    bf16x8 a = *(const bf16x8*)(arow + kk * 32);
#pragma unroll
    for (int c = 0; c < 8; ++c) {
      bf16x8 b = *(const bf16x8*)(brow + c * 16 * SP + kk * 32);
      acc[c] = __builtin_amdgcn_mfma_f32_16x16x32_bf16(a, b, acc[c], 0, 0, 0);
    }
  }
  // C/D layout: col = lane&15, row = quad*4 + reg
#pragma unroll
  for (int c = 0; c < 8; ++c) {
    int col = c * 16 + m16;
#pragma unroll
    for (int r = 0; r < 4; ++r) {
      int grow = row0 + wv * 16 + quad * 4 + r;
      if (grow < NN) {
        float v = acc[c][r];
        if (ADDP) v += b2f(P[(size_t)grow * 128 + col]);
        if (RELU) v = fmaxf(v, 0.f);
        if (OUT_BF16) ((u16*)Cv)[(size_t)grow * 128 + col] = f2b(v);
        else          ((float*)Cv)[(size_t)grow * 128 + col] = v;
      }
    }
  }
}

extern "C" void kernel_launch(void* const* d_in, const int* in_sizes, int n_in,
                              void* d_out, int out_size, void* d_ws, size_t ws_size,
                              hipStream_t stream) {
  const float* x_net   = (const float*)d_in[0];
  const float* x_cell  = (const float*)d_in[1];
  const float* Wp_net  = (const float*)d_in[2];
  const float* Wp_cell = (const float*)d_in[3];
  const float* Wg[3] = {(const float*)d_in[4], (const float*)d_in[7], (const float*)d_in[10]};
  const float* al[3] = {(const float*)d_in[5], (const float*)d_in[8], (const float*)d_in[11]};
  const float* ar[3] = {(const float*)d_in[6], (const float*)d_in[9], (const float*)d_in[12]};
  const float* Wl    = (const float*)d_in[13];
  const float* bias  = (const float*)d_in[14];
  const int* src[3] = {(const int*)d_in[15], (const int*)d_in[17], (const int*)d_in[19]};
  const int* dst[3] = {(const int*)d_in[16], (const int*)d_in[18], (const int*)d_in[20]};

  char* ws = (char*)d_ws;
  size_t off = 0;
  auto alloc = [&](size_t b) { void* p = ws + off; off = (off + b + 255) & ~(size_t)255; return p; };
  u16*  feat_net  = (u16*)alloc((size_t)NN * 128 * 2);
  u16*  feat_cell = (u16*)alloc((size_t)NN * 128 * 2);
  u16*  hbuf      = (u16*)alloc((size_t)NN * 128 * 2);
  u16*  P_net     = (u16*)alloc((size_t)NN * 128 * 2);
  u16*  P_cell    = (u16*)alloc((size_t)NN * 128 * 2);
  float* buf_net  = (float*)alloc((size_t)NN * 128 * 4);
  float* buf_cell = (float*)alloc((size_t)NN * 128 * 4);
  float* vecs     = (float*)alloc(6 * 128 * 4);
  float* logit    = (float*)alloc((size_t)6 * NN * 4);
  int*   deg      = (int*)alloc((size_t)3 * NN * 4);
  int*   cursor   = (int*)alloc((size_t)3 * NN * 4);
  int*   rowptr   = (int*)alloc((size_t)3 * (NN + 1) * 4);
  int2*  pairs    = (int2*)alloc((size_t)3 * NE * 8);
  // ~251 MB total

  hipMemsetAsync(buf_net, 0, (size_t)NN * 128 * 4, stream);
  hipMemsetAsync(buf_cell, 0, (size_t)NN * 128 * 4, stream);
  hipMemsetAsync(deg, 0, (size_t)3 * NN * 4, stream);

  proj_k<<<dim3(NN / 16, 2), 256, 0, stream>>>(x_net, x_cell, Wp_net, Wp_cell, feat_net, feat_cell);
  vec_k<<<6, 128, 0, stream>>>(Wg[0], al[0], ar[0], Wg[1], al[1], ar[1], Wg[2], al[2], ar[2], vecs);
  logits_k<<<dim3((NN + 255) / 256, 6), 256, 0, stream>>>(feat_net, feat_cell, vecs, logit);

  // CSR build (all 3 relations)
  hist_k<<<dim3((NE + 255) / 256, 3), 256, 0, stream>>>(dst[0], dst[1], dst[2], deg);
  scan_k<<<3, 1024, 0, stream>>>(deg, rowptr, cursor);
  scatter_k<<<dim3((NE + 255) / 256, 3), 256, 0, stream>>>(src[0], dst[0], src[1], dst[1], src[2], dst[2],
                                                           logit, cursor, pairs);

  const int gb = (NN + 63) / 64;  // 1563
  gemm_k<0, 0, 0, 0, 1><<<gb, 256, 0, stream>>>(feat_net, Wl, 256, 0, nullptr, nullptr, P_net);
  gemm_k<0, 0, 0, 0, 1><<<gb, 256, 0, stream>>>(feat_cell, Wl, 256, 0, nullptr, nullptr, P_cell);

  const u16* srcfeat[3] = {feat_cell, feat_net, feat_net};
  float* aggout[3] = {buf_net, buf_cell, buf_net};
  const int ab = (NN + 3) / 4;    // 25000
  for (int r = 0; r < 3; ++r) {
    gemm_k<0, 0, 0, 0, 1><<<gb, 256, 0, stream>>>(srcfeat[r], Wg[r], 128, 0, nullptr, nullptr, hbuf);
    agg_csr_k<<<ab, 256, 0, stream>>>(hbuf, pairs + (size_t)r * NE, rowptr + (size_t)r * (NN + 1), aggout[r]);
    if (r < 2) {
      gemm_k<1, 1, 1, 1, 0><<<gb, 256, 0, stream>>>(buf_net, Wl, 256, 128, bias, P_net, buf_net);
      gemm_k<1, 1, 1, 1, 0><<<gb, 256, 0, stream>>>(buf_cell, Wl, 256, 128, bias, P_cell, buf_cell);
    } else {
      float* out_f = (float*)d_out;  // [2,N,D] fp32
      gemm_k<1, 1, 1, 1, 0><<<gb, 256, 0, stream>>>(buf_net, Wl, 256, 128, bias, P_net, out_f);
      gemm_k<1, 1, 1, 1, 0><<<gb, 256, 0, stream>>>(buf_cell, Wl, 256, 128, bias, P_cell, out_f + (size_t)NN * 128);
    }
  }
}

// Round 4
// 968.498 us; speedup vs baseline: 1.4828x; 1.2539x over previous
//
#include <hip/hip_runtime.h>
#include <hip/hip_bf16.h>
#include <stdint.h>

// ParaGraph: 2 node types (net/cell, N=100000), 3 relations (E=600000 each), D=128.
// I/O FP32. Internals: bf16 MFMA GEMMs; CSR-gather softmax-aggregation (no fp32 atomics).
#define NN 100000
#define NE 600000
#define SP 136       // LDS row stride in ushorts: 128 + 8 pad
#define CHK 1024     // scan chunk size
#define NCH 98       // ceil(NN/CHK)

typedef unsigned short u16;
typedef unsigned int u32;
typedef __attribute__((ext_vector_type(8))) short short8;
typedef __attribute__((ext_vector_type(8))) __bf16 bf16x8;
typedef __attribute__((ext_vector_type(4))) float floatx4;

__device__ __forceinline__ float b2f(u16 u) {
  union { float f; u32 i; } c; c.i = ((u32)u) << 16; return c.f;
}
__device__ __forceinline__ u16 f2b(float f) {
  union { float f; u32 i; } c; c.f = f;
  u32 r = c.i + 0x7FFFu + ((c.i >> 16) & 1u);  // RNE
  return (u16)(r >> 16);
}

// ---------- feature projection: feat = x @ Wp.T, [N,16]x[16,128] -> bf16 [N,128]
__global__ __launch_bounds__(256) void proj_k(const float* __restrict__ x_net, const float* __restrict__ x_cell,
                                              const float* __restrict__ Wp_net, const float* __restrict__ Wp_cell,
                                              u16* __restrict__ feat_net, u16* __restrict__ feat_cell) {
  const float* x  = blockIdx.y ? x_cell : x_net;
  const float* Wp = blockIdx.y ? Wp_cell : Wp_net;
  u16* feat       = blockIdx.y ? feat_cell : feat_net;
  __shared__ float Ws[128 * 17];
  __shared__ float xs[16][17];
  int tid = threadIdx.x;
#pragma unroll
  for (int it = 0; it < 8; ++it) {
    int idx = it * 256 + tid;
    int j = idx >> 4, k = idx & 15;
    Ws[j * 17 + k] = Wp[idx];
  }
  int n0 = blockIdx.x * 16;
  { int nn = tid >> 4, k = tid & 15;
    xs[nn][k] = x[(size_t)(n0 + nn) * 16 + k]; }
  __syncthreads();
  int j = tid & 127, g = tid >> 7;
  float acc[8];
#pragma unroll
  for (int r = 0; r < 8; ++r) acc[r] = 0.f;
#pragma unroll
  for (int k = 0; k < 16; ++k) {
    float w = Ws[j * 17 + k];
#pragma unroll
    for (int r = 0; r < 8; ++r) acc[r] += xs[g * 8 + r][k] * w;
  }
#pragma unroll
  for (int r = 0; r < 8; ++r)
    feat[(size_t)(n0 + g * 8 + r) * 128 + j] = f2b(acc[r]);
}

// ---------- attention logit vectors: vecs[a] = Wg_r.T @ (al or ar), 6 x [128]
__global__ __launch_bounds__(128) void vec_k(const float* Wg0, const float* al0, const float* ar0,
                                             const float* Wg1, const float* al1, const float* ar1,
                                             const float* Wg2, const float* al2, const float* ar2,
                                             float* __restrict__ vecs) {
  int a = blockIdx.x;
  const float* W = (a < 2) ? Wg0 : (a < 4) ? Wg1 : Wg2;
  const float* v = (a == 0) ? al0 : (a == 1) ? ar0 : (a == 2) ? al1 : (a == 3) ? ar1 : (a == 4) ? al2 : ar2;
  int j = threadIdx.x;
  float s = 0.f;
  for (int i = 0; i < 128; ++i) s += W[i * 128 + j] * v[i];
  vecs[a * 128 + j] = s;
}

// ---------- per-node logits: outs[a][n] = dot(feat_type(a)[n], vecs[a])
__global__ __launch_bounds__(256) void logits_k(const u16* __restrict__ feat_net, const u16* __restrict__ feat_cell,
                                                const float* __restrict__ vecs, float* __restrict__ outs) {
  int a = blockIdx.y;
  const u16* f = (a == 0 || a == 3) ? feat_cell : feat_net;
  __shared__ float vs[128];
  if (threadIdx.x < 128) vs[threadIdx.x] = vecs[a * 128 + threadIdx.x];
  __syncthreads();
  int n = blockIdx.x * 256 + threadIdx.x;
  if (n >= NN) return;
  const u16* row = f + (size_t)n * 128;
  float s = 0.f;
#pragma unroll
  for (int k = 0; k < 128; k += 8) {
    short8 u = *(const short8*)(row + k);
#pragma unroll
    for (int t = 0; t < 8; ++t) s += b2f((u16)u[t]) * vs[k + t];
  }
  outs[(size_t)a * NN + n] = s;
}

// ---------- CSR build: histogram of dst
__global__ __launch_bounds__(256) void hist_k(const int* __restrict__ dst0, const int* __restrict__ dst1,
                                              const int* __restrict__ dst2, int* __restrict__ deg) {
  int r = blockIdx.y;
  const int* dst = (r == 0) ? dst0 : (r == 1) ? dst1 : dst2;
  int e = blockIdx.x * 256 + threadIdx.x;
  if (e >= NE) return;
  atomicAdd(&deg[r * NN + dst[e]], 1);
}

// ---------- scan phase A: chunk sums (grid = NCH x 3, 256 thr, 4 elems/thr)
__global__ __launch_bounds__(256) void scanA_k(const int* __restrict__ deg, int* __restrict__ psum) {
  int r = blockIdx.y, chunk = blockIdx.x, t = threadIdx.x;
  const int* d = deg + (size_t)r * NN;
  int base = chunk * CHK + t * 4;
  int s = 0;
#pragma unroll
  for (int i = 0; i < 4; ++i) { int idx = base + i; if (idx < NN) s += d[idx]; }
  __shared__ int ss[256];
  ss[t] = s; __syncthreads();
  for (int off = 128; off > 0; off >>= 1) {
    if (t < off) ss[t] += ss[t + off];
    __syncthreads();
  }
  if (t == 0) psum[r * NCH + chunk] = ss[0];
}

// ---------- scan phase B: exclusive-scan the NCH chunk sums per relation; write rp[NN]
__global__ __launch_bounds__(128) void scanB_k(const int* __restrict__ psum, int* __restrict__ psc,
                                               int* __restrict__ rowptr) {
  int r = blockIdx.x, t = threadIdx.x;
  __shared__ int ss[128];
  int v = (t < NCH) ? psum[r * NCH + t] : 0;
  ss[t] = v; __syncthreads();
  for (int off = 1; off < 128; off <<= 1) {
    int u = (t >= off) ? ss[t - off] : 0;
    __syncthreads();
    ss[t] += u;
    __syncthreads();
  }
  if (t < NCH) psc[r * NCH + t] = ss[t] - v;      // exclusive
  if (t == 127) rowptr[(size_t)r * (NN + 1) + NN] = ss[127];
}

// ---------- scan phase C: in-chunk exclusive scan + chunk offset -> rowptr & cursor
__global__ __launch_bounds__(256) void scanC_k(const int* __restrict__ deg, const int* __restrict__ psc,
                                               int* __restrict__ rowptr, int* __restrict__ cursor) {
  int r = blockIdx.y, chunk = blockIdx.x, t = threadIdx.x;
  const int* d = deg + (size_t)r * NN;
  int* rp = rowptr + (size_t)r * (NN + 1);
  int* cur = cursor + (size_t)r * NN;
  int base = chunk * CHK + t * 4;
  int v[4]; int ts = 0;
#pragma unroll
  for (int i = 0; i < 4; ++i) { int idx = base + i; v[i] = (idx < NN) ? d[idx] : 0; ts += v[i]; }
  __shared__ int ss[256];
  ss[t] = ts; __syncthreads();
  for (int off = 1; off < 256; off <<= 1) {
    int u = (t >= off) ? ss[t - off] : 0;
    __syncthreads();
    ss[t] += u;
    __syncthreads();
  }
  int run = ss[t] - ts + psc[r * NCH + chunk];
#pragma unroll
  for (int i = 0; i < 4; ++i) {
    int idx = base + i;
    if (idx < NN) { rp[idx] = run; cur[idx] = run; run += v[i]; }
  }
}

// ---------- CSR build: scatter {src, ex=exp(leaky(el+er))} into dst-sorted slots
__global__ __launch_bounds__(256) void scatter_k(const int* __restrict__ src0, const int* __restrict__ dst0,
                                                 const int* __restrict__ src1, const int* __restrict__ dst1,
                                                 const int* __restrict__ src2, const int* __restrict__ dst2,
                                                 const float* __restrict__ logit,
                                                 int* __restrict__ cursor, int2* __restrict__ pairs) {
  int r = blockIdx.y;
  const int* src = (r == 0) ? src0 : (r == 1) ? src1 : src2;
  const int* dst = (r == 0) ? dst0 : (r == 1) ? dst1 : dst2;
  int e = blockIdx.x * 256 + threadIdx.x;
  if (e >= NE) return;
  int sN = src[e], dN = dst[e];
  float t = logit[(size_t)(2 * r) * NN + sN] + logit[(size_t)(2 * r + 1) * NN + dN];
  float l = (t >= 0.f) ? t : 0.2f * t;          // leaky_relu 0.2
  float x = __expf(l);
  int pos = atomicAdd(&cursor[(size_t)r * NN + dN], 1);
  union { float f; int i; } c; c.f = x;
  pairs[(size_t)r * NE + pos] = make_int2(sN, c.i);
}

// ---------- aggregation: one wave per dst node; out[n] += (sum ex*h[src]) / (sum ex)
__global__ __launch_bounds__(256) void agg_csr_k(const u16* __restrict__ h, const int2* __restrict__ pairs,
                                                 const int* __restrict__ rp, float* __restrict__ out) {
  int n = blockIdx.x * 4 + (threadIdx.x >> 6);
  if (n >= NN) return;
  int lane = threadIdx.x & 63;
  int start = rp[n], end = rp[n + 1];
  if (start == end) return;
  float2 acc = make_float2(0.f, 0.f);
  float s = 0.f;
  for (int e = start; e < end; ++e) {
    int2 p = pairs[e];                          // broadcast
    union { int i; float f; } c; c.i = p.y;
    float x = c.f;
    s += x;
    u32 hv = *(const u32*)(h + (size_t)p.x * 128 + 2 * lane);
    acc.x += x * b2f((u16)(hv & 0xffff));
    acc.y += x * b2f((u16)(hv >> 16));
  }
  float inv = 1.f / s;
  float2* o = (float2*)(out + (size_t)n * 128 + 2 * lane);
  float2 prev = *o;
  prev.x += acc.x * inv; prev.y += acc.y * inv;
  *o = prev;
}

// ---------- MFMA GEMM: C[n][j] = act( P?[n][j] + sum_k (A[n][k]+bias?[k]) * W[j*ldw+woff+k] )
template<int A_F32, int BIAS, int ADDP, int RELU, int OUT_BF16>
__global__ __launch_bounds__(256) void gemm_k(const void* __restrict__ Av,
                                              const float* __restrict__ W, int ldw, int woff,
                                              const float* __restrict__ bias, const u16* __restrict__ P,
                                              void* __restrict__ Cv) {
  __shared__ u16 Alds[64 * SP];
  __shared__ u16 Wlds[128 * SP];
  const int tid = threadIdx.x;
  const int row0 = blockIdx.x * 64;
#pragma unroll
  for (int it = 0; it < 16; ++it) {
    int idx = it * 256 + tid;
    int r = idx >> 5, c = (idx & 31) << 2;
    float4 v = *(const float4*)(W + (size_t)r * ldw + woff + c);
    ushort4 p; p.x = f2b(v.x); p.y = f2b(v.y); p.z = f2b(v.z); p.w = f2b(v.w);
    *(ushort4*)(&Wlds[r * SP + c]) = p;
  }
  if (A_F32) {
    const float* A = (const float*)Av;
#pragma unroll
    for (int it = 0; it < 8; ++it) {
      int idx = it * 256 + tid;
      int r = idx >> 5, col = (idx & 31) << 2;
      int gr = row0 + r;
      float4 v = make_float4(0.f, 0.f, 0.f, 0.f);
      if (gr < NN) v = *(const float4*)(A + (size_t)gr * 128 + col);
      if (BIAS) { v.x += bias[col]; v.y += bias[col + 1]; v.z += bias[col + 2]; v.w += bias[col + 3]; }
      ushort4 p; p.x = f2b(v.x); p.y = f2b(v.y); p.z = f2b(v.z); p.w = f2b(v.w);
      *(ushort4*)(&Alds[r * SP + col]) = p;
    }
  } else {
    const u16* A = (const u16*)Av;
#pragma unroll
    for (int it = 0; it < 4; ++it) {
      int idx = it * 256 + tid;
      int r = idx >> 4, c = (idx & 15) << 3;
      int gr = row0 + r;
      short8 v = short8{0, 0, 0, 0, 0, 0, 0, 0};
      if (gr < NN) v = *(const short8*)(A + (size_t)gr * 128 + c);
      *(short8*)(&Alds[r * SP + c]) = v;
    }
  }
  __syncthreads();
  const int lane = tid & 63, wv = tid >> 6;
  const int m16 = lane & 15, quad = lane >> 4;
  floatx4 acc[8];
#pragma unroll
  for (int c = 0; c < 8; ++c) acc[c] = floatx4{0.f, 0.f, 0.f, 0.f};
  const u16* arow = &Alds[(wv * 16 + m16) * SP + quad * 8];
  const u16* brow = &Wlds[m16 * SP + quad * 8];
#pragma unroll
  for (int kk = 0; kk < 4; ++kk) {
    bf16x8 a = *(const bf16x8*)(arow + kk * 32);
#pragma unroll
    for (int c = 0; c < 8; ++c) {
      bf16x8 b = *(const bf16x8*)(brow + c * 16 * SP + kk * 32);
      acc[c] = __builtin_amdgcn_mfma_f32_16x16x32_bf16(a, b, acc[c], 0, 0, 0);
    }
  }
  // C/D layout: col = lane&15, row = quad*4 + reg
#pragma unroll
  for (int c = 0; c < 8; ++c) {
    int col = c * 16 + m16;
#pragma unroll
    for (int r = 0; r < 4; ++r) {
      int grow = row0 + wv * 16 + quad * 4 + r;
      if (grow < NN) {
        float v = acc[c][r];
        if (ADDP) v += b2f(P[(size_t)grow * 128 + col]);
        if (RELU) v = fmaxf(v, 0.f);
        if (OUT_BF16) ((u16*)Cv)[(size_t)grow * 128 + col] = f2b(v);
        else          ((float*)Cv)[(size_t)grow * 128 + col] = v;
      }
    }
  }
}

extern "C" void kernel_launch(void* const* d_in, const int* in_sizes, int n_in,
                              void* d_out, int out_size, void* d_ws, size_t ws_size,
                              hipStream_t stream) {
  const float* x_net   = (const float*)d_in[0];
  const float* x_cell  = (const float*)d_in[1];
  const float* Wp_net  = (const float*)d_in[2];
  const float* Wp_cell = (const float*)d_in[3];
  const float* Wg[3] = {(const float*)d_in[4], (const float*)d_in[7], (const float*)d_in[10]};
  const float* al[3] = {(const float*)d_in[5], (const float*)d_in[8], (const float*)d_in[11]};
  const float* ar[3] = {(const float*)d_in[6], (const float*)d_in[9], (const float*)d_in[12]};
  const float* Wl    = (const float*)d_in[13];
  const float* bias  = (const float*)d_in[14];
  const int* src[3] = {(const int*)d_in[15], (const int*)d_in[17], (const int*)d_in[19]};
  const int* dst[3] = {(const int*)d_in[16], (const int*)d_in[18], (const int*)d_in[20]};

  char* ws = (char*)d_ws;
  size_t off = 0;
  auto alloc = [&](size_t b) { void* p = ws + off; off = (off + b + 255) & ~(size_t)255; return p; };
  u16*  feat_net  = (u16*)alloc((size_t)NN * 128 * 2);
  u16*  feat_cell = (u16*)alloc((size_t)NN * 128 * 2);
  u16*  hbuf      = (u16*)alloc((size_t)NN * 128 * 2);
  u16*  P_net     = (u16*)alloc((size_t)NN * 128 * 2);
  u16*  P_cell    = (u16*)alloc((size_t)NN * 128 * 2);
  float* buf_net  = (float*)alloc((size_t)NN * 128 * 4);
  float* buf_cell = (float*)alloc((size_t)NN * 128 * 4);
  float* vecs     = (float*)alloc(6 * 128 * 4);
  float* logit    = (float*)alloc((size_t)6 * NN * 4);
  int*   deg      = (int*)alloc((size_t)3 * NN * 4);
  int*   cursor   = (int*)alloc((size_t)3 * NN * 4);
  int*   rowptr   = (int*)alloc((size_t)3 * (NN + 1) * 4);
  int*   psum     = (int*)alloc((size_t)3 * NCH * 4);
  int*   psc      = (int*)alloc((size_t)3 * NCH * 4);
  int2*  pairs    = (int2*)alloc((size_t)3 * NE * 8);

  hipMemsetAsync(buf_net, 0, (size_t)NN * 128 * 4, stream);
  hipMemsetAsync(buf_cell, 0, (size_t)NN * 128 * 4, stream);
  hipMemsetAsync(deg, 0, (size_t)3 * NN * 4, stream);

  proj_k<<<dim3(NN / 16, 2), 256, 0, stream>>>(x_net, x_cell, Wp_net, Wp_cell, feat_net, feat_cell);
  vec_k<<<6, 128, 0, stream>>>(Wg[0], al[0], ar[0], Wg[1], al[1], ar[1], Wg[2], al[2], ar[2], vecs);
  logits_k<<<dim3((NN + 255) / 256, 6), 256, 0, stream>>>(feat_net, feat_cell, vecs, logit);

  // CSR build (all 3 relations, multi-block scan)
  hist_k<<<dim3((NE + 255) / 256, 3), 256, 0, stream>>>(dst[0], dst[1], dst[2], deg);
  scanA_k<<<dim3(NCH, 3), 256, 0, stream>>>(deg, psum);
  scanB_k<<<3, 128, 0, stream>>>(psum, psc, rowptr);
  scanC_k<<<dim3(NCH, 3), 256, 0, stream>>>(deg, psc, rowptr, cursor);
  scatter_k<<<dim3((NE + 255) / 256, 3), 256, 0, stream>>>(src[0], dst[0], src[1], dst[1], src[2], dst[2],
                                                           logit, cursor, pairs);

  const int gb = (NN + 63) / 64;  // 1563
  gemm_k<0, 0, 0, 0, 1><<<gb, 256, 0, stream>>>(feat_net, Wl, 256, 0, nullptr, nullptr, P_net);
  gemm_k<0, 0, 0, 0, 1><<<gb, 256, 0, stream>>>(feat_cell, Wl, 256, 0, nullptr, nullptr, P_cell);

  const u16* srcfeat[3] = {feat_cell, feat_net, feat_net};
  float* aggout[3] = {buf_net, buf_cell, buf_net};
  const int ab = (NN + 3) / 4;    // 25000
  for (int r = 0; r < 3; ++r) {
    gemm_k<0, 0, 0, 0, 1><<<gb, 256, 0, stream>>>(srcfeat[r], Wg[r], 128, 0, nullptr, nullptr, hbuf);
    agg_csr_k<<<ab, 256, 0, stream>>>(hbuf, pairs + (size_t)r * NE, rowptr + (size_t)r * (NN + 1), aggout[r]);
    if (r < 2) {
      gemm_k<1, 1, 1, 1, 0><<<gb, 256, 0, stream>>>(buf_net, Wl, 256, 128, bias, P_net, buf_net);
      gemm_k<1, 1, 1, 1, 0><<<gb, 256, 0, stream>>>(buf_cell, Wl, 256, 128, bias, P_cell, buf_cell);
    } else {
      float* out_f = (float*)d_out;  // [2,N,D] fp32
      gemm_k<1, 1, 1, 1, 0><<<gb, 256, 0, stream>>>(buf_net, Wl, 256, 128, bias, P_net, out_f);
      gemm_k<1, 1, 1, 1, 0><<<gb, 256, 0, stream>>>(buf_cell, Wl, 256, 128, bias, P_cell, out_f + (size_t)NN * 128);
    }
  }
}